// Round 10
// baseline (260.181 us; speedup 1.0000x reference)
//
#include <hip/hip_runtime.h>

// PhaseCoherenceLoss: scalar reduction over (B, T=8192, 3) fp32 logits.
// pair (t,t+1): pt=argmax[t], pt1=argmax[t+1]; illegal[pt][pt1] ->
// loss += (max logit at t+1)^2, cnt++. out = cnt>0 ? 10*loss/cnt : 0.
// Illegal codes pt*3+pt1 in {2,3,6,7} -> bitmask 0xCC.
//
// R1: atomics serialized (392us) -> two-stage. R3-R7: four load structures
//   all ~74us cold. R8 probe: warm=31us (6.5 TB/s = ceiling) -> cold cost is
//   harness L3 state. R9: nontemporal loads + LDS staging -> cold ~58us
//   (dur 259). R10: drop the LDS staging round-trip (vmcnt drain + barrier
//   per block); direct nt dwordx3 at 12-B lane stride, successor via shfl,
//   512-thread blocks for deeper per-block miss queue.

#define NTHREADS  512
#define NWAVES    8
#define SLAB      4096          // timesteps per block
#define JITER     8             // SLAB / NTHREADS
#define TLEN      8192          // 2 slabs per row

typedef float f3v __attribute__((ext_vector_type(3), aligned(4)));

// pack (bits(max) & ~3) | argidx — strict > keeps first-max tie-break.
// 2 low mantissa bits dropped: 2^-21 rel err, vs 0.255 abs threshold.
__device__ __forceinline__ int argmax3_pack(f3v v) {
    float bm = v.x; int bi = 0;
    if (v.y > bm) { bm = v.y; bi = 1; }
    if (v.z > bm) { bm = v.z; bi = 2; }
    return (__float_as_int(bm) & ~3) | bi;
}

__global__ __launch_bounds__(NTHREADS) void pcl_main(const float* __restrict__ x,
                                                     float* __restrict__ part_loss,
                                                     unsigned int* __restrict__ part_cnt) {
    const int tid  = threadIdx.x;
    const int lane = tid & 63;
    const int wv   = tid >> 6;
    const float* xb = x + (size_t)blockIdx.x * SLAB * 3;

    // direct nt loads, lane-linear 12-B stride: wave = 768B contiguous/instr,
    // 24 independent loads issued per thread before first use.
    f3v own[JITER];
    #pragma unroll
    for (int j = 0; j < JITER; ++j)
        own[j] = __builtin_nontemporal_load((const f3v*)(xb + (size_t)3 * (tid + j * NTHREADS)));

    const bool has_next = ((blockIdx.x & 1u) == 0u);   // 2 slabs per row
    f3v nextv = own[0];
    if (tid == NTHREADS - 1 && has_next)
        nextv = __builtin_nontemporal_load((const f3v*)(xb + (size_t)3 * SLAB));

    int pk[JITER];
    #pragma unroll
    for (int j = 0; j < JITER; ++j) pk[j] = argmax3_pack(own[j]);

    // wave-boundary successor table: lane-0 packs of each wave
    __shared__ int sm[NWAVES][JITER];
    if (lane == 0) {
        #pragma unroll
        for (int j = 0; j < JITER; ++j) sm[wv][j] = pk[j];
    }
    __syncthreads();

    float loss = 0.0f;
    unsigned int cnt = 0;
    #pragma unroll
    for (int j = 0; j < JITER; ++j) {
        int npk = __shfl_down(pk[j], 1, 64);                 // successor = tid+1, same j
        if (lane == 63) {
            if (wv < NWAVES - 1)     npk = sm[wv + 1][j];    // next wave, same j
            else if (j < JITER - 1)  npk = sm[0][j + 1];     // tid 511 -> tid 0, j+1
            else                     npk = argmax3_pack(nextv); // cross-slab
        }
        bool valid = !(wv == NWAVES - 1 && lane == 63 && j == JITER - 1 && !has_next);
        if (valid) {
            int code = (pk[j] & 3) * 3 + (npk & 3);
            if ((0xCC >> code) & 1) {
                float nmx = __int_as_float(npk & ~3);
                loss = fmaf(nmx, nmx, loss);
                cnt++;
            }
        }
    }

    // wave + block reduce
    #pragma unroll
    for (int off = 32; off > 0; off >>= 1) {
        loss += __shfl_down(loss, off, 64);
        cnt  += __shfl_down(cnt,  off, 64);
    }
    __shared__ float        sl[NWAVES];
    __shared__ unsigned int sc[NWAVES];
    if (lane == 0) { sl[wv] = loss; sc[wv] = cnt; }
    __syncthreads();
    if (tid == 0) {
        float        L = 0.f;
        unsigned int C = 0;
        #pragma unroll
        for (int w = 0; w < NWAVES; ++w) { L += sl[w]; C += sc[w]; }
        part_loss[blockIdx.x] = L;
        part_cnt[blockIdx.x]  = C;
    }
}

__global__ __launch_bounds__(NTHREADS) void pcl_final(const float* __restrict__ part_loss,
                                                      const unsigned int* __restrict__ part_cnt,
                                                      float* __restrict__ out, int npart) {
    double L = 0.0;
    unsigned int C = 0;
    for (int i = threadIdx.x; i < npart; i += NTHREADS) {
        L += (double)part_loss[i];
        C += part_cnt[i];
    }
    #pragma unroll
    for (int off = 32; off > 0; off >>= 1) {
        L += __shfl_down(L, off, 64);
        C += __shfl_down(C, off, 64);
    }
    __shared__ double       sl[NWAVES];
    __shared__ unsigned int sc[NWAVES];
    int lane = threadIdx.x & 63, wid = threadIdx.x >> 6;
    if (lane == 0) { sl[wid] = L; sc[wid] = C; }
    __syncthreads();
    if (threadIdx.x == 0) {
        double       Lt = 0.0;
        unsigned int Ct = 0;
        #pragma unroll
        for (int w = 0; w < NWAVES; ++w) { Lt += sl[w]; Ct += sc[w]; }
        out[0] = (Ct > 0u) ? (float)(10.0 * Lt / (double)Ct) : 0.0f;
    }
}

extern "C" void kernel_launch(void* const* d_in, const int* in_sizes, int n_in,
                              void* d_out, int out_size, void* d_ws, size_t ws_size,
                              hipStream_t stream) {
    const float* x = (const float*)d_in[0];
    const int B = in_sizes[0] / (3 * TLEN);
    const int grid = B * (TLEN / SLAB);                // 4096 for B=2048

    float*        part_loss = (float*)d_ws;
    unsigned int* part_cnt  = (unsigned int*)((char*)d_ws + (size_t)grid * sizeof(float));

    // All partial slots written unconditionally each call -> no memset needed
    // despite the 0xAA ws re-poison.
    pcl_main<<<grid, NTHREADS, 0, stream>>>(x, part_loss, part_cnt);
    pcl_final<<<1, NTHREADS, 0, stream>>>(part_loss, part_cnt, (float*)d_out, grid);
}